// Round 1
// baseline (128.533 us; speedup 1.0000x reference)
//
#include <hip/hip_runtime.h>
#include <math.h>

#define BATCH 4
#define NPTS  8192      // N1 == N2
#define SEG   16        // candidate segments per direction
#define PPT   4         // points per thread
#define TPB   256

// L = candidates per segment
#define LSEG  (NPTS / SEG)   // 512

// ws layout:
//   pk1: float4[BATCH*NPTS]   @ 0          (512 KB)  [x,y,z,|p|^2] of xyz1
//   pk2: float4[BATCH*NPTS]   @ 512 KB     (512 KB)  same for xyz2
//   partial: float[SEG*BATCH*NPTS] @ 1 MB  (2 MB)    reused by both directions

__global__ __launch_bounds__(TPB) void pack_kernel(
    const float* __restrict__ xyz1, const float* __restrict__ xyz2,
    float4* __restrict__ pk1, float4* __restrict__ pk2,
    float* __restrict__ out) {
  int i = blockIdx.x * TPB + threadIdx.x;
  const int total = BATCH * NPTS;
  if (i == 0) out[0] = 0.0f;
  const float* src;
  float4* dst;
  int j;
  if (i < total) { src = xyz1; dst = pk1; j = i; }
  else           { src = xyz2; dst = pk2; j = i - total; }
  float x = src[3 * j + 0];
  float y = src[3 * j + 1];
  float z = src[3 * j + 2];
  dst[j] = make_float4(x, y, z, fmaf(x, x, fmaf(y, y, z * z)));
}

// Each thread: P points (register-resident), scans one candidate segment.
// partial[s * (BATCH*NPTS) + b*NPTS + i] = min over segment s of (sq2_j - 2*dot)
__global__ __launch_bounds__(TPB) void min_kernel(
    const float4* __restrict__ pts, const float4* __restrict__ cand,
    float* __restrict__ partial) {
  const int b   = blockIdx.z;
  const int s   = blockIdx.y;
  const int tid = threadIdx.x;
  const int base = blockIdx.x * (TPB * PPT) + tid;   // point index within set

  const float4* __restrict__ cb = cand + b * NPTS + s * LSEG;

  float nx[PPT], ny[PPT], nz[PPT], m[PPT];
#pragma unroll
  for (int p = 0; p < PPT; ++p) {
    float4 q = pts[b * NPTS + base + p * TPB];
    nx[p] = -2.0f * q.x;
    ny[p] = -2.0f * q.y;
    nz[p] = -2.0f * q.z;
    m[p]  = INFINITY;
  }

#pragma unroll 4
  for (int j = 0; j < LSEG; ++j) {
    float4 c = cb[j];   // wave-uniform address -> broadcast load, L1-resident
#pragma unroll
    for (int p = 0; p < PPT; ++p) {
      float d = fmaf(nx[p], c.x, fmaf(ny[p], c.y, fmaf(nz[p], c.z, c.w)));
      m[p] = fminf(m[p], d);
    }
  }

#pragma unroll
  for (int p = 0; p < PPT; ++p)
    partial[(size_t)s * (BATCH * NPTS) + b * NPTS + base + p * TPB] = m[p];
}

// Reduce over segments, add |p|^2, mean-accumulate into out[0].
__global__ __launch_bounds__(TPB) void finalize_kernel(
    const float* __restrict__ partial, const float4* __restrict__ pts,
    float* __restrict__ out, float scale) {
  int idx = blockIdx.x * TPB + threadIdx.x;   // 0 .. BATCH*NPTS-1
  float m = INFINITY;
#pragma unroll
  for (int s = 0; s < SEG; ++s)
    m = fminf(m, partial[(size_t)s * (BATCH * NPTS) + idx]);
  float v = (m + pts[idx].w) * scale;

  // wave64 reduce
  for (int off = 32; off > 0; off >>= 1) v += __shfl_down(v, off);
  __shared__ float ls[TPB / 64];
  if ((threadIdx.x & 63) == 0) ls[threadIdx.x >> 6] = v;
  __syncthreads();
  if (threadIdx.x == 0) {
    float t = 0.0f;
#pragma unroll
    for (int w = 0; w < TPB / 64; ++w) t += ls[w];
    atomicAdd(out, t);
  }
}

extern "C" void kernel_launch(void* const* d_in, const int* in_sizes, int n_in,
                              void* d_out, int out_size, void* d_ws, size_t ws_size,
                              hipStream_t stream) {
  const float* xyz1 = (const float*)d_in[0];
  const float* xyz2 = (const float*)d_in[1];
  float* out = (float*)d_out;

  char* ws = (char*)d_ws;
  float4* pk1     = (float4*)(ws);
  float4* pk2     = (float4*)(ws + (size_t)BATCH * NPTS * sizeof(float4));
  float*  partial = (float*)(ws + (size_t)2 * BATCH * NPTS * sizeof(float4));

  const int total = BATCH * NPTS;

  // 1) pack both sets + zero out[0]
  pack_kernel<<<dim3(2 * total / TPB), dim3(TPB), 0, stream>>>(xyz1, xyz2, pk1, pk2, out);

  dim3 mgrid(NPTS / (TPB * PPT), SEG, BATCH);   // 8 x 16 x 4
  const float scale = 1.0f / (float)total;

  // 2) direction 1: for each xyz1 point, min over xyz2
  min_kernel<<<mgrid, dim3(TPB), 0, stream>>>(pk1, pk2, partial);
  finalize_kernel<<<dim3(total / TPB), dim3(TPB), 0, stream>>>(partial, pk1, out, scale);

  // 3) direction 2: for each xyz2 point, min over xyz1 (reuses partial buffer)
  min_kernel<<<mgrid, dim3(TPB), 0, stream>>>(pk2, pk1, partial);
  finalize_kernel<<<dim3(total / TPB), dim3(TPB), 0, stream>>>(partial, pk2, out, scale);
}

// Round 2
// 76.601 us; speedup vs baseline: 1.6780x; 1.6780x over previous
//
#include <hip/hip_runtime.h>
#include <math.h>

#define BATCH 4
#define NPTS  8192      // N1 == N2
#define SEG   64        // candidate segments per direction
#define PPT   8         // points per thread
#define TPB   256

#define LSEG  (NPTS / SEG)          // 128 candidates per segment
#define TOTAL (BATCH * NPTS)        // 32768 points per set

// ws layout:
//   pk1:    float4[TOTAL]  @ 0        (512 KB)  [x,y,z,|p|^2] of xyz1
//   pk2:    float4[TOTAL]  @ 512 KB   (512 KB)  same for xyz2   (contiguous after pk1)
//   minbuf: uint[2*TOTAL]  @ 1 MB     (256 KB)  ordered-uint running min, dir1 then dir2

// monotone float->u32: preserves ordering under unsigned compare
__device__ __forceinline__ unsigned f2ord(float f) {
  unsigned b = __float_as_uint(f);
  return ((int)b >= 0) ? (b ^ 0x80000000u) : ~b;
}
__device__ __forceinline__ float ord2f(unsigned k) {
  unsigned b = (k & 0x80000000u) ? (k ^ 0x80000000u) : ~k;
  return __uint_as_float(b);
}

__global__ __launch_bounds__(TPB) void pack_kernel(
    const float* __restrict__ xyz1, const float* __restrict__ xyz2,
    float4* __restrict__ pk1, float4* __restrict__ pk2,
    unsigned* __restrict__ minbuf, float* __restrict__ out) {
  int i = blockIdx.x * TPB + threadIdx.x;   // 0 .. 2*TOTAL-1
  if (i == 0) out[0] = 0.0f;
  minbuf[i] = 0xFFFFFFFFu;                  // +max key
  const float* src;
  float4* dst;
  int j;
  if (i < TOTAL) { src = xyz1; dst = pk1; j = i; }
  else           { src = xyz2; dst = pk2; j = i - TOTAL; }
  float x = src[3 * j + 0];
  float y = src[3 * j + 1];
  float z = src[3 * j + 2];
  dst[j] = make_float4(x, y, z, fmaf(x, x, fmaf(y, y, z * z)));
}

// Each thread: PPT points (register-resident), scans one candidate segment,
// atomicMin's the ordered-uint partial min into minbuf.
__global__ __launch_bounds__(TPB) void min_kernel(
    const float4* __restrict__ pts, const float4* __restrict__ cand,
    unsigned* __restrict__ minbuf) {
  const int b    = blockIdx.z;
  const int s    = blockIdx.y;
  const int tid  = threadIdx.x;
  const int base = blockIdx.x * (TPB * PPT) + tid;   // point index within set

  const float4* __restrict__ cb = cand + b * NPTS + s * LSEG;

  float nx[PPT], ny[PPT], nz[PPT], m[PPT];
#pragma unroll
  for (int p = 0; p < PPT; ++p) {
    float4 q = pts[b * NPTS + base + p * TPB];
    nx[p] = -2.0f * q.x;
    ny[p] = -2.0f * q.y;
    nz[p] = -2.0f * q.z;
    m[p]  = INFINITY;
  }

#pragma unroll 4
  for (int j = 0; j < LSEG; ++j) {
    float4 c = cb[j];   // wave-uniform -> scalar loads, L2-resident
#pragma unroll
    for (int p = 0; p < PPT; ++p) {
      float d = fmaf(nx[p], c.x, fmaf(ny[p], c.y, fmaf(nz[p], c.z, c.w)));
      m[p] = fminf(m[p], d);
    }
  }

  unsigned* __restrict__ mb = minbuf + b * NPTS;
#pragma unroll
  for (int p = 0; p < PPT; ++p)
    atomicMin(&mb[base + p * TPB], f2ord(m[p]));
}

// One kernel for both directions: decode key, add |p|^2, mean-accumulate.
__global__ __launch_bounds__(TPB) void finalize_kernel(
    const unsigned* __restrict__ minbuf, const float4* __restrict__ pk_all,
    float* __restrict__ out, float scale) {
  int idx = blockIdx.x * TPB + threadIdx.x;   // 0 .. 2*TOTAL-1
  float v = (ord2f(minbuf[idx]) + pk_all[idx].w) * scale;

  for (int off = 32; off > 0; off >>= 1) v += __shfl_down(v, off);
  __shared__ float ls[TPB / 64];
  if ((threadIdx.x & 63) == 0) ls[threadIdx.x >> 6] = v;
  __syncthreads();
  if (threadIdx.x == 0) {
    float t = 0.0f;
#pragma unroll
    for (int w = 0; w < TPB / 64; ++w) t += ls[w];
    atomicAdd(out, t);
  }
}

extern "C" void kernel_launch(void* const* d_in, const int* in_sizes, int n_in,
                              void* d_out, int out_size, void* d_ws, size_t ws_size,
                              hipStream_t stream) {
  const float* xyz1 = (const float*)d_in[0];
  const float* xyz2 = (const float*)d_in[1];
  float* out = (float*)d_out;

  char* ws = (char*)d_ws;
  float4*   pk1    = (float4*)(ws);
  float4*   pk2    = (float4*)(ws + (size_t)TOTAL * sizeof(float4));
  unsigned* minbuf = (unsigned*)(ws + (size_t)2 * TOTAL * sizeof(float4));

  // 1) pack both sets + init minbuf + zero out[0]   (2*TOTAL threads)
  pack_kernel<<<dim3(2 * TOTAL / TPB), dim3(TPB), 0, stream>>>(
      xyz1, xyz2, pk1, pk2, minbuf, out);

  dim3 mgrid(NPTS / (TPB * PPT), SEG, BATCH);   // 4 x 64 x 4 = 1024 blocks
  // 2) dir 1: for each xyz1 point, min over xyz2 -> minbuf[0:TOTAL]
  min_kernel<<<mgrid, dim3(TPB), 0, stream>>>(pk1, pk2, minbuf);
  // 3) dir 2: for each xyz2 point, min over xyz1 -> minbuf[TOTAL:2*TOTAL]
  min_kernel<<<mgrid, dim3(TPB), 0, stream>>>(pk2, pk1, minbuf + TOTAL);

  // 4) finalize both directions into out[0]
  const float scale = 1.0f / (float)TOTAL;
  finalize_kernel<<<dim3(2 * TOTAL / TPB), dim3(TPB), 0, stream>>>(
      minbuf, pk1, out, scale);
}

// Round 3
// 65.912 us; speedup vs baseline: 1.9501x; 1.1622x over previous
//
#include <hip/hip_runtime.h>
#include <math.h>

#define BATCH 4
#define NPTS  8192      // N1 == N2
#define SEG   64        // candidate segments per direction
#define PPT   8         // points per thread
#define TPB   256

#define LSEG  (NPTS / SEG)          // 128 candidates per segment
#define TOTAL (BATCH * NPTS)        // 32768 points per set

// ws layout:
//   pk1:    float4[TOTAL]  @ 0        (512 KB)  [x,y,z,|p|^2] of xyz1
//   pk2:    float4[TOTAL]  @ 512 KB   (512 KB)  same for xyz2
//   minbuf: uint[2*TOTAL]  @ 1 MB     (256 KB)  ordered-uint running min, dir1 then dir2

// monotone float->u32: preserves ordering under unsigned compare
__device__ __forceinline__ unsigned f2ord(float f) {
  unsigned b = __float_as_uint(f);
  return ((int)b >= 0) ? (b ^ 0x80000000u) : ~b;
}
__device__ __forceinline__ float ord2f(unsigned k) {
  unsigned b = (k & 0x80000000u) ? (k ^ 0x80000000u) : ~k;
  return __uint_as_float(b);
}

__global__ __launch_bounds__(TPB) void pack_kernel(
    const float* __restrict__ xyz1, const float* __restrict__ xyz2,
    float4* __restrict__ pk1, float4* __restrict__ pk2,
    unsigned* __restrict__ minbuf, float* __restrict__ out) {
  int i = blockIdx.x * TPB + threadIdx.x;   // 0 .. 2*TOTAL-1
  if (i == 0) out[0] = 0.0f;
  minbuf[i] = 0xFFFFFFFFu;                  // +max key
  const float* src;
  float4* dst;
  int j;
  if (i < TOTAL) { src = xyz1; dst = pk1; j = i; }
  else           { src = xyz2; dst = pk2; j = i - TOTAL; }
  float x = src[3 * j + 0];
  float y = src[3 * j + 1];
  float z = src[3 * j + 2];
  dst[j] = make_float4(x, y, z, fmaf(x, x, fmaf(y, y, z * z)));
}

// Both directions in one launch: blockIdx.z in [0,2*BATCH): b = z&3, dir = z>>2.
// Each thread: PPT points (register-resident), scans one candidate segment,
// atomicMin's the ordered-uint partial min into minbuf.
__global__ __launch_bounds__(TPB) void min_kernel(
    const float4* __restrict__ pk1, const float4* __restrict__ pk2,
    unsigned* __restrict__ minbuf) {
  const int z    = blockIdx.z;
  const int b    = z & (BATCH - 1);
  const int dir  = z >> 2;                  // 0: rows from pk1, cands pk2; 1: swapped
  const int s    = blockIdx.y;
  const int tid  = threadIdx.x;
  const int base = blockIdx.x * (TPB * PPT) + tid;   // point index within set

  const float4* __restrict__ pts  = dir ? pk2 : pk1;
  const float4* __restrict__ cand = dir ? pk1 : pk2;
  unsigned* __restrict__ mb = minbuf + dir * TOTAL + b * NPTS;

  const float4* __restrict__ cb = cand + b * NPTS + s * LSEG;

  float nx[PPT], ny[PPT], nz[PPT], m[PPT];
#pragma unroll
  for (int p = 0; p < PPT; ++p) {
    float4 q = pts[b * NPTS + base + p * TPB];
    nx[p] = -2.0f * q.x;
    ny[p] = -2.0f * q.y;
    nz[p] = -2.0f * q.z;
    m[p]  = INFINITY;
  }

#pragma unroll 8
  for (int j = 0; j < LSEG; ++j) {
    float4 c = cb[j];   // wave-uniform -> scalar loads, scalar-cache resident
#pragma unroll
    for (int p = 0; p < PPT; ++p) {
      float d = fmaf(nx[p], c.x, fmaf(ny[p], c.y, fmaf(nz[p], c.z, c.w)));
      m[p] = fminf(m[p], d);
    }
  }

#pragma unroll
  for (int p = 0; p < PPT; ++p)
    atomicMin(&mb[base + p * TPB], f2ord(m[p]));
}

// One kernel for both directions: decode key, add |p|^2, mean-accumulate.
__global__ __launch_bounds__(TPB) void finalize_kernel(
    const unsigned* __restrict__ minbuf, const float4* __restrict__ pk_all,
    float* __restrict__ out, float scale) {
  int idx = blockIdx.x * TPB + threadIdx.x;   // 0 .. 2*TOTAL-1
  float v = (ord2f(minbuf[idx]) + pk_all[idx].w) * scale;

  for (int off = 32; off > 0; off >>= 1) v += __shfl_down(v, off);
  __shared__ float ls[TPB / 64];
  if ((threadIdx.x & 63) == 0) ls[threadIdx.x >> 6] = v;
  __syncthreads();
  if (threadIdx.x == 0) {
    float t = 0.0f;
#pragma unroll
    for (int w = 0; w < TPB / 64; ++w) t += ls[w];
    atomicAdd(out, t);
  }
}

extern "C" void kernel_launch(void* const* d_in, const int* in_sizes, int n_in,
                              void* d_out, int out_size, void* d_ws, size_t ws_size,
                              hipStream_t stream) {
  const float* xyz1 = (const float*)d_in[0];
  const float* xyz2 = (const float*)d_in[1];
  float* out = (float*)d_out;

  char* ws = (char*)d_ws;
  float4*   pk1    = (float4*)(ws);
  float4*   pk2    = (float4*)(ws + (size_t)TOTAL * sizeof(float4));
  unsigned* minbuf = (unsigned*)(ws + (size_t)2 * TOTAL * sizeof(float4));

  // 1) pack both sets + init minbuf + zero out[0]   (2*TOTAL threads)
  pack_kernel<<<dim3(2 * TOTAL / TPB), dim3(TPB), 0, stream>>>(
      xyz1, xyz2, pk1, pk2, minbuf, out);

  // 2) both directions in ONE launch: 4 x 64 x 8 = 2048 blocks -> ~8 waves/SIMD
  dim3 mgrid(NPTS / (TPB * PPT), SEG, 2 * BATCH);
  min_kernel<<<mgrid, dim3(TPB), 0, stream>>>(pk1, pk2, minbuf);

  // 3) finalize both directions into out[0]
  const float scale = 1.0f / (float)TOTAL;
  finalize_kernel<<<dim3(2 * TOTAL / TPB), dim3(TPB), 0, stream>>>(
      minbuf, pk1, out, scale);
}

// Round 4
// 60.357 us; speedup vs baseline: 2.1295x; 1.0920x over previous
//
#include <hip/hip_runtime.h>
#include <math.h>

#define BATCH 4
#define NPTS  8192
#define TOTAL (BATCH * NPTS)            // 32768 points per set
#define TPB   256

#define ROWT   4                        // 32-row tiles per wave
#define BWAVES 4                        // waves per block
#define ROWS_PER_BLOCK (32 * ROWT * BWAVES)   // 512
#define COLCH  8                        // column chunks per batch
#define COLS_PER_CHUNK (NPTS / COLCH)   // 1024
#define NCT    (COLS_PER_CHUNK / 32)    // 32 col-tiles per wave sweep

typedef __bf16 bf16v8 __attribute__((ext_vector_type(8)));
typedef float  f32x16 __attribute__((ext_vector_type(16)));

// ws layout:
//   Apk: ushort[TOTAL*16] @ 0    (1 MB)  set1 A-form K-vectors
//   Bpk: ushort[TOTAL*16] @ 1 MB (1 MB)  set2 B-form K-vectors
//   minbuf: uint[2*TOTAL] @ 2 MB (256 KB) rows (dist1) then cols (dist2), ordered-uint

__device__ __forceinline__ unsigned f2ord(float f) {
  unsigned b = __float_as_uint(f);
  return ((int)b >= 0) ? (b ^ 0x80000000u) : ~b;
}
__device__ __forceinline__ float ord2f(unsigned k) {
  unsigned b = (k & 0x80000000u) ? (k ^ 0x80000000u) : ~k;
  return __uint_as_float(b);
}
__device__ __forceinline__ unsigned short f2bf(float f) {   // RNE
  unsigned u = __float_as_uint(f);
  return (unsigned short)((u + 0x7fffu + ((u >> 16) & 1u)) >> 16);
}
__device__ __forceinline__ float bf2f(unsigned short h) {
  return __uint_as_float(((unsigned)h) << 16);
}

// K-slot pairing (A[k]*B[k]):
//  k0-2 : ah  * ch      k3-5 : al * ch      k6-8 : ah * cl     (c = -2b)
//  k9,10: sq1h,sq1l * 1,1                   k11,12: 1,1 * sq2h,sq2l
//  k13-15: 0
__global__ __launch_bounds__(TPB) void pack_kernel(
    const float* __restrict__ x1, const float* __restrict__ x2,
    unsigned short* __restrict__ Apk, unsigned short* __restrict__ Bpk,
    unsigned* __restrict__ minbuf, float* __restrict__ out) {
  int i = blockIdx.x * TPB + threadIdx.x;   // 0 .. 2*TOTAL-1
  if (i == 0) out[0] = 0.0f;
  minbuf[i] = 0xFFFFFFFFu;

  bool isB = (i >= TOTAL);
  int j = isB ? i - TOTAL : i;
  const float* src = isB ? x2 : x1;
  float x = src[3 * j + 0];
  float y = src[3 * j + 1];
  float z = src[3 * j + 2];
  float sq = fmaf(x, x, fmaf(y, y, z * z));
  unsigned short sh = f2bf(sq);
  unsigned short sl = f2bf(sq - bf2f(sh));
  const unsigned short one = 0x3F80;

  unsigned short v[16];
  if (!isB) {
    unsigned short hx = f2bf(x), hy = f2bf(y), hz = f2bf(z);
    unsigned short lx = f2bf(x - bf2f(hx)), ly = f2bf(y - bf2f(hy)), lz = f2bf(z - bf2f(hz));
    v[0] = hx; v[1] = hy; v[2] = hz;
    v[3] = lx; v[4] = ly; v[5] = lz;
    v[6] = hx; v[7] = hy; v[8] = hz;
    v[9] = sh; v[10] = sl; v[11] = one; v[12] = one;
    v[13] = v[14] = v[15] = 0;
  } else {
    float cx = -2.0f * x, cy = -2.0f * y, cz = -2.0f * z;
    unsigned short hx = f2bf(cx), hy = f2bf(cy), hz = f2bf(cz);
    unsigned short lx = f2bf(cx - bf2f(hx)), ly = f2bf(cy - bf2f(hy)), lz = f2bf(cz - bf2f(hz));
    v[0] = hx; v[1] = hy; v[2] = hz;
    v[3] = hx; v[4] = hy; v[5] = hz;
    v[6] = lx; v[7] = ly; v[8] = lz;
    v[9] = one; v[10] = one; v[11] = sh; v[12] = sl;
    v[13] = v[14] = v[15] = 0;
  }
  uint4* dst = (uint4*)((isB ? Bpk : Apk) + (size_t)j * 16);
  uint4 w0, w1;
  w0.x = v[0] | ((unsigned)v[1] << 16);  w0.y = v[2] | ((unsigned)v[3] << 16);
  w0.z = v[4] | ((unsigned)v[5] << 16);  w0.w = v[6] | ((unsigned)v[7] << 16);
  w1.x = v[8] | ((unsigned)v[9] << 16);  w1.y = v[10] | ((unsigned)v[11] << 16);
  w1.z = v[12] | ((unsigned)v[13] << 16); w1.w = v[14] | ((unsigned)v[15] << 16);
  dst[0] = w0; dst[1] = w1;
}

// One pass over the pair space: row-mins -> dist1, col-mins -> dist2.
__global__ __launch_bounds__(TPB) void min_kernel(
    const unsigned short* __restrict__ Apk, const unsigned short* __restrict__ Bpk,
    unsigned* __restrict__ minbuf) {
  __shared__ unsigned colmin[COLS_PER_CHUNK];
  const int b   = blockIdx.z;
  const int tid = threadIdx.x;
  for (int k = tid; k < COLS_PER_CHUNK; k += TPB) colmin[k] = 0xFFFFFFFFu;
  __syncthreads();

  const int wave = tid >> 6, lane = tid & 63;
  const int g = lane >> 5, l31 = lane & 31;
  const int rowbase = blockIdx.x * ROWS_PER_BLOCK + wave * (32 * ROWT);
  const int colbase = blockIdx.y * COLS_PER_CHUNK;

  // A fragments: lane holds row rowbase+r*32+l31, k-group g (8 bf16 = 16 B)
  bf16v8 af[ROWT];
#pragma unroll
  for (int r = 0; r < ROWT; ++r) {
    int row = rowbase + r * 32 + l31;
    af[r] = *(const bf16v8*)(Apk + (size_t)(b * NPTS + row) * 16 + g * 8);
  }
  f32x16 zc;
#pragma unroll
  for (int q = 0; q < 16; ++q) zc[q] = 0.0f;
  float rowacc[ROWT][16];
#pragma unroll
  for (int r = 0; r < ROWT; ++r)
#pragma unroll
    for (int q = 0; q < 16; ++q) rowacc[r][q] = INFINITY;

  const unsigned short* Bb = Bpk + (size_t)(b * NPTS + colbase) * 16 + g * 8;
  bf16v8 bcur = *(const bf16v8*)(Bb + (size_t)l31 * 16);

  for (int ct = 0; ct < NCT; ++ct) {
    int ctn = (ct + 1 < NCT) ? ct + 1 : ct;
    bf16v8 bnext = *(const bf16v8*)(Bb + (size_t)(ctn * 32 + l31) * 16);

    float colt = INFINITY;
#pragma unroll
    for (int r = 0; r < ROWT; ++r) {
      f32x16 acc = __builtin_amdgcn_mfma_f32_32x32x16_bf16(af[r], bcur, zc, 0, 0, 0);
#pragma unroll
      for (int q = 0; q < 16; ++q) rowacc[r][q] = fminf(rowacc[r][q], acc[q]);
      float t0 = fminf(fminf(acc[0], acc[1]), fminf(acc[2], acc[3]));
      float t1 = fminf(fminf(acc[4], acc[5]), fminf(acc[6], acc[7]));
      float t2 = fminf(fminf(acc[8], acc[9]), fminf(acc[10], acc[11]));
      float t3 = fminf(fminf(acc[12], acc[13]), fminf(acc[14], acc[15]));
      colt = fminf(colt, fminf(fminf(t0, t1), fminf(t2, t3)));
    }
    // lanes l and l+32 hold the same column -> combine, then one LDS atomic
    colt = fminf(colt, __shfl_xor(colt, 32));
    unsigned key = f2ord(colt);
    if (g == 0) atomicMin(&colmin[ct * 32 + l31], key);
    bcur = bnext;
  }

  // row side: butterfly min across the 32 lanes of each half-wave
#pragma unroll
  for (int r = 0; r < ROWT; ++r)
#pragma unroll
    for (int q = 0; q < 16; ++q) {
      float v = rowacc[r][q];
      v = fminf(v, __shfl_xor(v, 16));
      v = fminf(v, __shfl_xor(v, 8));
      v = fminf(v, __shfl_xor(v, 4));
      v = fminf(v, __shfl_xor(v, 2));
      v = fminf(v, __shfl_xor(v, 1));
      rowacc[r][q] = v;
    }
  if (l31 == 0) {
#pragma unroll
    for (int r = 0; r < ROWT; ++r)
#pragma unroll
      for (int q = 0; q < 16; ++q) {
        int row = rowbase + r * 32 + (q & 3) + 8 * (q >> 2) + 4 * g;
        atomicMin(&minbuf[b * NPTS + row], f2ord(rowacc[r][q]));
      }
  }

  __syncthreads();
  for (int k = tid; k < COLS_PER_CHUNK; k += TPB)
    atomicMin(&minbuf[TOTAL + b * NPTS + colbase + k], colmin[k]);
}

__global__ __launch_bounds__(TPB) void finalize_kernel(
    const unsigned* __restrict__ minbuf, float* __restrict__ out, float scale) {
  int idx = blockIdx.x * TPB + threadIdx.x;   // 0 .. 2*TOTAL-1
  float v = ord2f(minbuf[idx]) * scale;
  for (int off = 32; off > 0; off >>= 1) v += __shfl_down(v, off);
  __shared__ float ls[TPB / 64];
  if ((threadIdx.x & 63) == 0) ls[threadIdx.x >> 6] = v;
  __syncthreads();
  if (threadIdx.x == 0) {
    float t = 0.0f;
#pragma unroll
    for (int w = 0; w < TPB / 64; ++w) t += ls[w];
    atomicAdd(out, t);
  }
}

extern "C" void kernel_launch(void* const* d_in, const int* in_sizes, int n_in,
                              void* d_out, int out_size, void* d_ws, size_t ws_size,
                              hipStream_t stream) {
  const float* xyz1 = (const float*)d_in[0];
  const float* xyz2 = (const float*)d_in[1];
  float* out = (float*)d_out;

  char* ws = (char*)d_ws;
  unsigned short* Apk = (unsigned short*)(ws);
  unsigned short* Bpk = (unsigned short*)(ws + (size_t)TOTAL * 32);
  unsigned*     minbuf = (unsigned*)(ws + (size_t)2 * TOTAL * 32);

  // 1) pack K-vectors + init minbuf + zero out
  pack_kernel<<<dim3(2 * TOTAL / TPB), dim3(TPB), 0, stream>>>(
      xyz1, xyz2, Apk, Bpk, minbuf, out);

  // 2) single pass: rows (dist1) + cols (dist2)
  dim3 mgrid(NPTS / ROWS_PER_BLOCK, COLCH, BATCH);   // 16 x 8 x 4 = 512 blocks
  min_kernel<<<mgrid, dim3(TPB), 0, stream>>>(Apk, Bpk, minbuf);

  // 3) finalize: mean(dist1) + mean(dist2)
  const float scale = 1.0f / (float)TOTAL;
  finalize_kernel<<<dim3(2 * TOTAL / TPB), dim3(TPB), 0, stream>>>(minbuf, out, scale);
}

// Round 5
// 43.087 us; speedup vs baseline: 2.9831x; 1.4008x over previous
//
#include <hip/hip_runtime.h>
#include <math.h>

#define BATCH 4
#define NPTS  8192
#define TOTAL (BATCH * NPTS)            // 32768 points per set
#define TPB   256

#define ROWT   2                        // 32-row tiles per wave
#define BWAVES 4                        // waves per block
#define ROWS_PER_BLOCK (32 * ROWT * BWAVES)   // 256
#define COLCH  8                        // column chunks per batch
#define COLS_PER_CHUNK (NPTS / COLCH)   // 1024
#define NCT    (COLS_PER_CHUNK / 32)    // 32 col-tiles per sweep
#define NCTP   (NCT / 2)                // 16 col-tile PAIRS

typedef __bf16 bf16v8 __attribute__((ext_vector_type(8)));
typedef float  f32x16 __attribute__((ext_vector_type(16)));

// ws layout:
//   Apk: ushort[TOTAL*16] @ 0    (1 MB)
//   Bpk: ushort[TOTAL*16] @ 1 MB (1 MB)
//   minbuf: uint[2*TOTAL] @ 2 MB (256 KB) rows (dist1) then cols (dist2)

__device__ __forceinline__ unsigned f2ord(float f) {
  unsigned b = __float_as_uint(f);
  return ((int)b >= 0) ? (b ^ 0x80000000u) : ~b;
}
__device__ __forceinline__ float ord2f(unsigned k) {
  unsigned b = (k & 0x80000000u) ? (k ^ 0x80000000u) : ~k;
  return __uint_as_float(b);
}
__device__ __forceinline__ unsigned short f2bf(float f) {   // RNE
  unsigned u = __float_as_uint(f);
  return (unsigned short)((u + 0x7fffu + ((u >> 16) & 1u)) >> 16);
}
__device__ __forceinline__ float bf2f(unsigned short h) {
  return __uint_as_float(((unsigned)h) << 16);
}
__device__ __forceinline__ float min3f(float a, float b, float c) {
  float d;
  asm("v_min3_f32 %0, %1, %2, %3" : "=v"(d) : "v"(a), "v"(b), "v"(c));
  return d;
}
// min3-fold a 16-elem acc into colt (8 ops)
__device__ __forceinline__ float coltree(const f32x16& a, float colt) {
  float t0 = min3f(a[0], a[1], a[2]);
  float t1 = min3f(a[3], a[4], a[5]);
  float t2 = min3f(a[6], a[7], a[8]);
  float t3 = min3f(a[9], a[10], a[11]);
  float t4 = min3f(a[12], a[13], a[14]);
  return min3f(colt, min3f(t0, t1, a[15]), min3f(t2, t3, t4));
}

// K-slot pairing (A[k]*B[k]):
//  k0-2: ah*ch   k3-5: al*ch   k6-8: ah*cl   (c = -2b)
//  k9,10: sq1h,sq1l * 1,1      k11,12: 1,1 * sq2h,sq2l     k13-15: 0
__global__ __launch_bounds__(TPB) void pack_kernel(
    const float* __restrict__ x1, const float* __restrict__ x2,
    unsigned short* __restrict__ Apk, unsigned short* __restrict__ Bpk,
    unsigned* __restrict__ minbuf, float* __restrict__ out) {
  int i = blockIdx.x * TPB + threadIdx.x;   // 0 .. 2*TOTAL-1
  if (i == 0) out[0] = 0.0f;
  minbuf[i] = 0xFFFFFFFFu;

  bool isB = (i >= TOTAL);
  int j = isB ? i - TOTAL : i;
  const float* src = isB ? x2 : x1;
  float x = src[3 * j + 0];
  float y = src[3 * j + 1];
  float z = src[3 * j + 2];
  float sq = fmaf(x, x, fmaf(y, y, z * z));
  unsigned short sh = f2bf(sq);
  unsigned short sl = f2bf(sq - bf2f(sh));
  const unsigned short one = 0x3F80;

  unsigned short v[16];
  if (!isB) {
    unsigned short hx = f2bf(x), hy = f2bf(y), hz = f2bf(z);
    unsigned short lx = f2bf(x - bf2f(hx)), ly = f2bf(y - bf2f(hy)), lz = f2bf(z - bf2f(hz));
    v[0] = hx; v[1] = hy; v[2] = hz;
    v[3] = lx; v[4] = ly; v[5] = lz;
    v[6] = hx; v[7] = hy; v[8] = hz;
    v[9] = sh; v[10] = sl; v[11] = one; v[12] = one;
    v[13] = v[14] = v[15] = 0;
  } else {
    float cx = -2.0f * x, cy = -2.0f * y, cz = -2.0f * z;
    unsigned short hx = f2bf(cx), hy = f2bf(cy), hz = f2bf(cz);
    unsigned short lx = f2bf(cx - bf2f(hx)), ly = f2bf(cy - bf2f(hy)), lz = f2bf(cz - bf2f(hz));
    v[0] = hx; v[1] = hy; v[2] = hz;
    v[3] = hx; v[4] = hy; v[5] = hz;
    v[6] = lx; v[7] = ly; v[8] = lz;
    v[9] = one; v[10] = one; v[11] = sh; v[12] = sl;
    v[13] = v[14] = v[15] = 0;
  }
  uint4* dst = (uint4*)((isB ? Bpk : Apk) + (size_t)j * 16);
  uint4 w0, w1;
  w0.x = v[0] | ((unsigned)v[1] << 16);  w0.y = v[2] | ((unsigned)v[3] << 16);
  w0.z = v[4] | ((unsigned)v[5] << 16);  w0.w = v[6] | ((unsigned)v[7] << 16);
  w1.x = v[8] | ((unsigned)v[9] << 16);  w1.y = v[10] | ((unsigned)v[11] << 16);
  w1.z = v[12] | ((unsigned)v[13] << 16); w1.w = v[14] | ((unsigned)v[15] << 16);
  dst[0] = w0; dst[1] = w1;
}

// One pass over the pair space: row-mins -> dist1, col-mins -> dist2.
// Col tiles processed in PAIRS so row accumulation uses v_min3.
__global__ __launch_bounds__(TPB) void min_kernel(
    const unsigned short* __restrict__ Apk, const unsigned short* __restrict__ Bpk,
    unsigned* __restrict__ minbuf) {
  __shared__ unsigned colmin[COLS_PER_CHUNK];
  const int b   = blockIdx.z;
  const int tid = threadIdx.x;
  for (int k = tid; k < COLS_PER_CHUNK; k += TPB) colmin[k] = 0xFFFFFFFFu;
  __syncthreads();

  const int wave = tid >> 6, lane = tid & 63;
  const int g = lane >> 5, l31 = lane & 31;
  const int rowbase = blockIdx.x * ROWS_PER_BLOCK + wave * (32 * ROWT);
  const int colbase = blockIdx.y * COLS_PER_CHUNK;

  // A fragments: lane (g,l31) holds row rowbase+r*32+l31, k-group g
  bf16v8 af[ROWT];
#pragma unroll
  for (int r = 0; r < ROWT; ++r)
    af[r] = *(const bf16v8*)(Apk + (size_t)(b * NPTS + rowbase + r * 32 + l31) * 16 + g * 8);

  f32x16 zc;
#pragma unroll
  for (int q = 0; q < 16; ++q) zc[q] = 0.0f;
  float rowacc[ROWT][16];
#pragma unroll
  for (int r = 0; r < ROWT; ++r)
#pragma unroll
    for (int q = 0; q < 16; ++q) rowacc[r][q] = INFINITY;

  // B fragments, bf16v8 element index = point*2 + g; tile stride = 64 elems
  const bf16v8* bp = (const bf16v8*)Bpk + (size_t)(b * NPTS + colbase + l31) * 2 + g;

  bf16v8 b0 = bp[0], b1 = bp[64];
  for (int ctp = 0; ctp < NCTP; ++ctp) {
    bf16v8 n0 = b0, n1 = b1;
    if (ctp + 1 < NCTP) { n0 = bp[128]; n1 = bp[192]; }

    float colt0 = INFINITY, colt1 = INFINITY;
#pragma unroll
    for (int r = 0; r < ROWT; ++r) {
      f32x16 aA = __builtin_amdgcn_mfma_f32_32x32x16_bf16(af[r], b0, zc, 0, 0, 0);
      f32x16 aB = __builtin_amdgcn_mfma_f32_32x32x16_bf16(af[r], b1, zc, 0, 0, 0);
#pragma unroll
      for (int q = 0; q < 16; ++q)
        rowacc[r][q] = min3f(rowacc[r][q], aA[q], aB[q]);
      colt0 = coltree(aA, colt0);
      colt1 = coltree(aB, colt1);
    }
    // lanes l31 and l31+32 cover complementary row-subsets of the same column
    colt0 = fminf(colt0, __shfl_xor(colt0, 32));
    colt1 = fminf(colt1, __shfl_xor(colt1, 32));
    if (g == 0) {
      atomicMin(&colmin[(2 * ctp + 0) * 32 + l31], f2ord(colt0));
      atomicMin(&colmin[(2 * ctp + 1) * 32 + l31], f2ord(colt1));
    }
    b0 = n0; b1 = n1;
    bp += 128;
  }

  // row side: butterfly min across the 32 lanes of each half-wave
#pragma unroll
  for (int r = 0; r < ROWT; ++r)
#pragma unroll
    for (int q = 0; q < 16; ++q) {
      float v = rowacc[r][q];
      v = fminf(v, __shfl_xor(v, 16));
      v = fminf(v, __shfl_xor(v, 8));
      v = fminf(v, __shfl_xor(v, 4));
      v = fminf(v, __shfl_xor(v, 2));
      v = fminf(v, __shfl_xor(v, 1));
      rowacc[r][q] = v;
    }
  if (l31 == 0) {
#pragma unroll
    for (int r = 0; r < ROWT; ++r)
#pragma unroll
      for (int q = 0; q < 16; ++q) {
        int row = rowbase + r * 32 + (q & 3) + 8 * (q >> 2) + 4 * g;
        atomicMin(&minbuf[b * NPTS + row], f2ord(rowacc[r][q]));
      }
  }

  __syncthreads();
  for (int k = tid; k < COLS_PER_CHUNK; k += TPB)
    atomicMin(&minbuf[TOTAL + b * NPTS + colbase + k], colmin[k]);
}

__global__ __launch_bounds__(TPB) void finalize_kernel(
    const unsigned* __restrict__ minbuf, float* __restrict__ out, float scale) {
  int idx = blockIdx.x * TPB + threadIdx.x;   // 0 .. 2*TOTAL-1
  float v = ord2f(minbuf[idx]) * scale;
  for (int off = 32; off > 0; off >>= 1) v += __shfl_down(v, off);
  __shared__ float ls[TPB / 64];
  if ((threadIdx.x & 63) == 0) ls[threadIdx.x >> 6] = v;
  __syncthreads();
  if (threadIdx.x == 0) {
    float t = 0.0f;
#pragma unroll
    for (int w = 0; w < TPB / 64; ++w) t += ls[w];
    atomicAdd(out, t);
  }
}

extern "C" void kernel_launch(void* const* d_in, const int* in_sizes, int n_in,
                              void* d_out, int out_size, void* d_ws, size_t ws_size,
                              hipStream_t stream) {
  const float* xyz1 = (const float*)d_in[0];
  const float* xyz2 = (const float*)d_in[1];
  float* out = (float*)d_out;

  char* ws = (char*)d_ws;
  unsigned short* Apk = (unsigned short*)(ws);
  unsigned short* Bpk = (unsigned short*)(ws + (size_t)TOTAL * 32);
  unsigned*    minbuf = (unsigned*)(ws + (size_t)2 * TOTAL * 32);

  // 1) pack K-vectors + init minbuf + zero out
  pack_kernel<<<dim3(2 * TOTAL / TPB), dim3(TPB), 0, stream>>>(
      xyz1, xyz2, Apk, Bpk, minbuf, out);

  // 2) single pass: rows (dist1) + cols (dist2)
  dim3 mgrid(NPTS / ROWS_PER_BLOCK, COLCH, BATCH);   // 32 x 8 x 4 = 1024 blocks
  min_kernel<<<mgrid, dim3(TPB), 0, stream>>>(Apk, Bpk, minbuf);

  // 3) finalize: mean(dist1) + mean(dist2)
  const float scale = 1.0f / (float)TOTAL;
  finalize_kernel<<<dim3(2 * TOTAL / TPB), dim3(TPB), 0, stream>>>(minbuf, out, scale);
}

// Round 6
// 39.498 us; speedup vs baseline: 3.2542x; 1.0909x over previous
//
#include <hip/hip_runtime.h>
#include <math.h>

#define BATCH 4
#define NPTS  8192
#define TOTAL (BATCH * NPTS)            // 32768 points per set
#define TPB   256

#define CT     4                        // fixed col-tiles per wave (32 cols each)
#define WPB    (TPB / 64)               // 4 waves per block
#define COLS_PER_WAVE  (32 * CT)        // 128
#define COLS_PER_BLOCK (COLS_PER_WAVE * WPB)  // 512
#define ROWCH  8                        // swept-row chunks
#define SWEEP  (NPTS / ROWCH)           // 1024 rows swept per wave
#define NT     (SWEEP / 32)             // 32 A-tiles per sweep

typedef __bf16 bf16v8 __attribute__((ext_vector_type(8)));
typedef float  f32x16 __attribute__((ext_vector_type(16)));

// ws layout:
//   Af: ushort[2*TOTAL*16] @ 0    (2 MB)  A-form K-vectors, set1 then set2
//   Bf: ushort[2*TOTAL*16] @ 2 MB (2 MB)  B-form K-vectors, set1 then set2
//   minbuf: uint[2*TOTAL]  @ 4 MB (256 KB) dist1 (set1 pts) then dist2 (set2 pts)

__device__ __forceinline__ unsigned f2ord(float f) {
  unsigned b = __float_as_uint(f);
  return ((int)b >= 0) ? (b ^ 0x80000000u) : ~b;
}
__device__ __forceinline__ float ord2f(unsigned k) {
  unsigned b = (k & 0x80000000u) ? (k ^ 0x80000000u) : ~k;
  return __uint_as_float(b);
}
__device__ __forceinline__ unsigned short f2bf(float f) {   // RNE
  unsigned u = __float_as_uint(f);
  return (unsigned short)((u + 0x7fffu + ((u >> 16) & 1u)) >> 16);
}
__device__ __forceinline__ float bf2f(unsigned short h) {
  return __uint_as_float(((unsigned)h) << 16);
}
__device__ __forceinline__ float min3f(float a, float b, float c) {
  float d;
  asm("v_min3_f32 %0, %1, %2, %3" : "=v"(d) : "v"(a), "v"(b), "v"(c));
  return d;
}
// min over 16 acc elements folded with carry-in (8 x v_min3)
__device__ __forceinline__ float coltree(const f32x16& a, float colt) {
  float t0 = min3f(a[0], a[1], a[2]);
  float t1 = min3f(a[3], a[4], a[5]);
  float t2 = min3f(a[6], a[7], a[8]);
  float t3 = min3f(a[9], a[10], a[11]);
  float t4 = min3f(a[12], a[13], a[14]);
  return min3f(colt, min3f(t0, t1, a[15]), min3f(t2, t3, t4));
}

// K-slot pairing (A[k]*B[k]), verified absmax 0 in R4/R5:
//  k0-2: ah*ch   k3-5: al*ch   k6-8: ah*cl   (c = -2b)
//  k9,10: sq_a{h,l} * 1,1      k11,12: 1,1 * sq_b{h,l}     k13-15: 0
__global__ __launch_bounds__(TPB) void pack_kernel(
    const float* __restrict__ x1, const float* __restrict__ x2,
    unsigned short* __restrict__ Af, unsigned short* __restrict__ Bf,
    unsigned* __restrict__ minbuf, float* __restrict__ out) {
  int i = blockIdx.x * TPB + threadIdx.x;   // 0 .. 2*TOTAL-1  (set-major)
  if (i == 0) out[0] = 0.0f;
  minbuf[i] = 0xFFFFFFFFu;

  bool s2 = (i >= TOTAL);
  int j = s2 ? i - TOTAL : i;
  const float* src = s2 ? x2 : x1;
  float x = src[3 * j + 0];
  float y = src[3 * j + 1];
  float z = src[3 * j + 2];
  float sq = fmaf(x, x, fmaf(y, y, z * z));
  unsigned short sh = f2bf(sq);
  unsigned short sl = f2bf(sq - bf2f(sh));
  const unsigned short one = 0x3F80;

  unsigned short hx = f2bf(x), hy = f2bf(y), hz = f2bf(z);
  unsigned short lx = f2bf(x - bf2f(hx)), ly = f2bf(y - bf2f(hy)), lz = f2bf(z - bf2f(hz));
  float cx = -2.0f * x, cy = -2.0f * y, cz = -2.0f * z;
  unsigned short chx = f2bf(cx), chy = f2bf(cy), chz = f2bf(cz);
  unsigned short clx = f2bf(cx - bf2f(chx)), cly = f2bf(cy - bf2f(chy)), clz = f2bf(cz - bf2f(chz));

  // A-form
  {
    unsigned short v[16] = {hx, hy, hz, lx, ly, lz, hx, hy, hz,
                            sh, sl, one, one, 0, 0, 0};
    uint4* dst = (uint4*)(Af + (size_t)i * 16);
    uint4 w0, w1;
    w0.x = v[0] | ((unsigned)v[1] << 16);  w0.y = v[2] | ((unsigned)v[3] << 16);
    w0.z = v[4] | ((unsigned)v[5] << 16);  w0.w = v[6] | ((unsigned)v[7] << 16);
    w1.x = v[8] | ((unsigned)v[9] << 16);  w1.y = v[10] | ((unsigned)v[11] << 16);
    w1.z = v[12] | ((unsigned)v[13] << 16); w1.w = v[14] | ((unsigned)v[15] << 16);
    dst[0] = w0; dst[1] = w1;
  }
  // B-form
  {
    unsigned short v[16] = {chx, chy, chz, chx, chy, chz, clx, cly, clz,
                            one, one, sh, sl, 0, 0, 0};
    uint4* dst = (uint4*)(Bf + (size_t)i * 16);
    uint4 w0, w1;
    w0.x = v[0] | ((unsigned)v[1] << 16);  w0.y = v[2] | ((unsigned)v[3] << 16);
    w0.z = v[4] | ((unsigned)v[5] << 16);  w0.w = v[6] | ((unsigned)v[7] << 16);
    w1.x = v[8] | ((unsigned)v[9] << 16);  w1.y = v[10] | ((unsigned)v[11] << 16);
    w1.z = v[12] | ((unsigned)v[13] << 16); w1.w = v[14] | ((unsigned)v[15] << 16);
    dst[0] = w0; dst[1] = w1;
  }
}

// Col-min-only pass, both directions via blockIdx.z.
// dir=0: cols = set1 (B-form), sweep set2 (A-form) -> dist1
// dir=1: cols = set2,          sweep set1          -> dist2
__global__ __launch_bounds__(TPB) void min_kernel(
    const unsigned short* __restrict__ Af, const unsigned short* __restrict__ Bf,
    unsigned* __restrict__ minbuf) {
  const int z   = blockIdx.z;
  const int b   = z & (BATCH - 1);
  const int dir = z >> 2;
  const int tid = threadIdx.x;
  const int wave = tid >> 6, lane = tid & 63;
  const int g = lane >> 5, l31 = lane & 31;

  const int colset = dir * TOTAL;          // offset of the col (target) set
  const int rowset = TOTAL - colset;       // offset of the swept set
  const int colbase = blockIdx.x * COLS_PER_BLOCK + wave * COLS_PER_WAVE;
  const int rowbase = blockIdx.y * SWEEP;

  // fixed B fragments: CT col-tiles
  const bf16v8* bv = (const bf16v8*)Bf;
  bf16v8 bfr[CT];
#pragma unroll
  for (int t = 0; t < CT; ++t)
    bfr[t] = bv[(size_t)(colset + b * NPTS + colbase + t * 32 + l31) * 2 + g];

  f32x16 zc;
#pragma unroll
  for (int q = 0; q < 16; ++q) zc[q] = 0.0f;
  float colacc[CT];
#pragma unroll
  for (int t = 0; t < CT; ++t) colacc[t] = INFINITY;

  // swept A fragments
  const bf16v8* ap = (const bf16v8*)Af + (size_t)(rowset + b * NPTS + rowbase + l31) * 2 + g;

  bf16v8 acur = ap[0];
  for (int ti = 0; ti < NT; ++ti) {
    bf16v8 anext = acur;
    if (ti + 1 < NT) anext = ap[64];
#pragma unroll
    for (int t = 0; t < CT; ++t) {
      f32x16 acc = __builtin_amdgcn_mfma_f32_32x32x16_bf16(acur, bfr[t], zc, 0, 0, 0);
      colacc[t] = coltree(acc, colacc[t]);
    }
    acur = anext;
    ap += 64;
  }

  // tail: merge g-halves (rows split across lane>>5), one masked atomic per tile
#pragma unroll
  for (int t = 0; t < CT; ++t) {
    float m = fminf(colacc[t], __shfl_xor(colacc[t], 32));
    if (g == 0)
      atomicMin(&minbuf[colset + b * NPTS + colbase + t * 32 + l31], f2ord(m));
  }
}

__global__ __launch_bounds__(TPB) void finalize_kernel(
    const unsigned* __restrict__ minbuf, float* __restrict__ out, float scale) {
  int idx = blockIdx.x * TPB + threadIdx.x;   // 0 .. 2*TOTAL-1
  float v = ord2f(minbuf[idx]) * scale;
  for (int off = 32; off > 0; off >>= 1) v += __shfl_down(v, off);
  __shared__ float ls[TPB / 64];
  if ((threadIdx.x & 63) == 0) ls[threadIdx.x >> 6] = v;
  __syncthreads();
  if (threadIdx.x == 0) {
    float t = 0.0f;
#pragma unroll
    for (int w = 0; w < TPB / 64; ++w) t += ls[w];
    atomicAdd(out, t);
  }
}

extern "C" void kernel_launch(void* const* d_in, const int* in_sizes, int n_in,
                              void* d_out, int out_size, void* d_ws, size_t ws_size,
                              hipStream_t stream) {
  const float* xyz1 = (const float*)d_in[0];
  const float* xyz2 = (const float*)d_in[1];
  float* out = (float*)d_out;

  char* ws = (char*)d_ws;
  unsigned short* Af = (unsigned short*)(ws);
  unsigned short* Bf = (unsigned short*)(ws + (size_t)2 * TOTAL * 32);
  unsigned*   minbuf = (unsigned*)(ws + (size_t)4 * TOTAL * 32);

  // 1) pack A/B forms for both sets + init minbuf + zero out
  pack_kernel<<<dim3(2 * TOTAL / TPB), dim3(TPB), 0, stream>>>(
      xyz1, xyz2, Af, Bf, minbuf, out);

  // 2) both directions, col-min only: 16 x 8 x 8 = 1024 blocks
  dim3 mgrid(NPTS / COLS_PER_BLOCK, ROWCH, 2 * BATCH);
  min_kernel<<<mgrid, dim3(TPB), 0, stream>>>(Af, Bf, minbuf);

  // 3) finalize: mean(dist1) + mean(dist2)
  const float scale = 1.0f / (float)TOTAL;
  finalize_kernel<<<dim3(2 * TOTAL / TPB), dim3(TPB), 0, stream>>>(minbuf, out, scale);
}

// Round 7
// 39.355 us; speedup vs baseline: 3.2659x; 1.0036x over previous
//
#include <hip/hip_runtime.h>
#include <math.h>

#define BATCH 4
#define NPTS  8192
#define TOTAL (BATCH * NPTS)            // 32768 points per set
#define TPB   256

#define CT     4                        // fixed col-tiles per wave (32 cols each)
#define WPB    (TPB / 64)               // 4 waves per block
#define COLS_PER_WAVE  (32 * CT)        // 128
#define COLS_PER_BLOCK (COLS_PER_WAVE * WPB)  // 512
#define ROWCH  16                       // swept-row chunks  (R7: 8 -> 16, 2048 blocks = 8 waves/SIMD)
#define SWEEP  (NPTS / ROWCH)           // 512 rows swept per wave
#define NT     (SWEEP / 32)             // 16 A-tiles per sweep

typedef __bf16 bf16v8 __attribute__((ext_vector_type(8)));
typedef float  f32x16 __attribute__((ext_vector_type(16)));

// ws layout:
//   Af: ushort[2*TOTAL*16] @ 0    (2 MB)  A-form K-vectors, set1 then set2
//   Bf: ushort[2*TOTAL*16] @ 2 MB (2 MB)  B-form K-vectors, set1 then set2
//   minbuf: uint[2*TOTAL]  @ 4 MB (256 KB) dist1 then dist2
//   (min_kernel prefetch may over-read Af by <=2KB into Bf -- mapped, harmless)

__device__ __forceinline__ unsigned f2ord(float f) {
  unsigned b = __float_as_uint(f);
  return ((int)b >= 0) ? (b ^ 0x80000000u) : ~b;
}
__device__ __forceinline__ float ord2f(unsigned k) {
  unsigned b = (k & 0x80000000u) ? (k ^ 0x80000000u) : ~k;
  return __uint_as_float(b);
}
__device__ __forceinline__ unsigned short f2bf(float f) {   // RNE
  unsigned u = __float_as_uint(f);
  return (unsigned short)((u + 0x7fffu + ((u >> 16) & 1u)) >> 16);
}
__device__ __forceinline__ float bf2f(unsigned short h) {
  return __uint_as_float(((unsigned)h) << 16);
}
__device__ __forceinline__ float min3f(float a, float b, float c) {
  float d;
  asm("v_min3_f32 %0, %1, %2, %3" : "=v"(d) : "v"(a), "v"(b), "v"(c));
  return d;
}
// min over 16 acc elements folded with carry-in (8 x v_min3)
__device__ __forceinline__ float coltree(const f32x16& a, float colt) {
  float t0 = min3f(a[0], a[1], a[2]);
  float t1 = min3f(a[3], a[4], a[5]);
  float t2 = min3f(a[6], a[7], a[8]);
  float t3 = min3f(a[9], a[10], a[11]);
  float t4 = min3f(a[12], a[13], a[14]);
  return min3f(colt, min3f(t0, t1, a[15]), min3f(t2, t3, t4));
}

// K-slot pairing (A[k]*B[k]), verified absmax 0 since R4:
//  k0-2: ah*ch   k3-5: al*ch   k6-8: ah*cl   (c = -2b)
//  k9,10: sq_a{h,l} * 1,1      k11,12: 1,1 * sq_b{h,l}     k13-15: 0
__global__ __launch_bounds__(TPB) void pack_kernel(
    const float* __restrict__ x1, const float* __restrict__ x2,
    unsigned short* __restrict__ Af, unsigned short* __restrict__ Bf,
    unsigned* __restrict__ minbuf, float* __restrict__ out) {
  int i = blockIdx.x * TPB + threadIdx.x;   // 0 .. 2*TOTAL-1  (set-major)
  if (i == 0) out[0] = 0.0f;
  minbuf[i] = 0xFFFFFFFFu;

  bool s2 = (i >= TOTAL);
  int j = s2 ? i - TOTAL : i;
  const float* src = s2 ? x2 : x1;
  float x = src[3 * j + 0];
  float y = src[3 * j + 1];
  float z = src[3 * j + 2];
  float sq = fmaf(x, x, fmaf(y, y, z * z));
  unsigned short sh = f2bf(sq);
  unsigned short sl = f2bf(sq - bf2f(sh));
  const unsigned short one = 0x3F80;

  unsigned short hx = f2bf(x), hy = f2bf(y), hz = f2bf(z);
  unsigned short lx = f2bf(x - bf2f(hx)), ly = f2bf(y - bf2f(hy)), lz = f2bf(z - bf2f(hz));
  float cx = -2.0f * x, cy = -2.0f * y, cz = -2.0f * z;
  unsigned short chx = f2bf(cx), chy = f2bf(cy), chz = f2bf(cz);
  unsigned short clx = f2bf(cx - bf2f(chx)), cly = f2bf(cy - bf2f(chy)), clz = f2bf(cz - bf2f(chz));

  // A-form
  {
    unsigned short v[16] = {hx, hy, hz, lx, ly, lz, hx, hy, hz,
                            sh, sl, one, one, 0, 0, 0};
    uint4* dst = (uint4*)(Af + (size_t)i * 16);
    uint4 w0, w1;
    w0.x = v[0] | ((unsigned)v[1] << 16);  w0.y = v[2] | ((unsigned)v[3] << 16);
    w0.z = v[4] | ((unsigned)v[5] << 16);  w0.w = v[6] | ((unsigned)v[7] << 16);
    w1.x = v[8] | ((unsigned)v[9] << 16);  w1.y = v[10] | ((unsigned)v[11] << 16);
    w1.z = v[12] | ((unsigned)v[13] << 16); w1.w = v[14] | ((unsigned)v[15] << 16);
    dst[0] = w0; dst[1] = w1;
  }
  // B-form
  {
    unsigned short v[16] = {chx, chy, chz, chx, chy, chz, clx, cly, clz,
                            one, one, sh, sl, 0, 0, 0};
    uint4* dst = (uint4*)(Bf + (size_t)i * 16);
    uint4 w0, w1;
    w0.x = v[0] | ((unsigned)v[1] << 16);  w0.y = v[2] | ((unsigned)v[3] << 16);
    w0.z = v[4] | ((unsigned)v[5] << 16);  w0.w = v[6] | ((unsigned)v[7] << 16);
    w1.x = v[8] | ((unsigned)v[9] << 16);  w1.y = v[10] | ((unsigned)v[11] << 16);
    w1.z = v[12] | ((unsigned)v[13] << 16); w1.w = v[14] | ((unsigned)v[15] << 16);
    dst[0] = w0; dst[1] = w1;
  }
}

// Col-min-only pass, both directions via blockIdx.z.
// dir=0: cols = set1 (B-form), sweep set2 (A-form) -> dist1
// dir=1: cols = set2,          sweep set1          -> dist2
__global__ __launch_bounds__(TPB) void min_kernel(
    const unsigned short* __restrict__ Af, const unsigned short* __restrict__ Bf,
    unsigned* __restrict__ minbuf) {
  const int z   = blockIdx.z;
  const int b   = z & (BATCH - 1);
  const int dir = z >> 2;
  const int tid = threadIdx.x;
  const int wave = tid >> 6, lane = tid & 63;
  const int g = lane >> 5, l31 = lane & 31;

  const int colset = dir * TOTAL;          // offset of the col (target) set
  const int rowset = TOTAL - colset;       // offset of the swept set
  const int colbase = blockIdx.x * COLS_PER_BLOCK + wave * COLS_PER_WAVE;
  const int rowbase = blockIdx.y * SWEEP;

  // fixed B fragments: CT col-tiles
  const bf16v8* bv = (const bf16v8*)Bf;
  bf16v8 bfr[CT];
#pragma unroll
  for (int t = 0; t < CT; ++t)
    bfr[t] = bv[(size_t)(colset + b * NPTS + colbase + t * 32 + l31) * 2 + g];

  f32x16 zc;
#pragma unroll
  for (int q = 0; q < 16; ++q) zc[q] = 0.0f;
  float colacc[CT];
#pragma unroll
  for (int t = 0; t < CT; ++t) colacc[t] = INFINITY;

  // swept A fragments; unconditional 1-tile-ahead prefetch (safe over-read)
  const bf16v8* ap = (const bf16v8*)Af + (size_t)(rowset + b * NPTS + rowbase + l31) * 2 + g;

  bf16v8 acur = ap[0];
  for (int ti = 0; ti < NT; ++ti) {
    bf16v8 anext = ap[64];                 // prefetch next tile (last iter: dead)
#pragma unroll
    for (int t = 0; t < CT; ++t) {
      f32x16 acc = __builtin_amdgcn_mfma_f32_32x32x16_bf16(acur, bfr[t], zc, 0, 0, 0);
      colacc[t] = coltree(acc, colacc[t]);
    }
    acur = anext;
    ap += 64;
  }

  // tail: merge g-halves (rows split across lane>>5), one masked atomic per tile
#pragma unroll
  for (int t = 0; t < CT; ++t) {
    float m = fminf(colacc[t], __shfl_xor(colacc[t], 32));
    if (g == 0)
      atomicMin(&minbuf[colset + b * NPTS + colbase + t * 32 + l31], f2ord(m));
  }
}

__global__ __launch_bounds__(TPB) void finalize_kernel(
    const unsigned* __restrict__ minbuf, float* __restrict__ out, float scale) {
  int idx = blockIdx.x * TPB + threadIdx.x;   // 0 .. 2*TOTAL-1
  float v = ord2f(minbuf[idx]) * scale;
  for (int off = 32; off > 0; off >>= 1) v += __shfl_down(v, off);
  __shared__ float ls[TPB / 64];
  if ((threadIdx.x & 63) == 0) ls[threadIdx.x >> 6] = v;
  __syncthreads();
  if (threadIdx.x == 0) {
    float t = 0.0f;
#pragma unroll
    for (int w = 0; w < TPB / 64; ++w) t += ls[w];
    atomicAdd(out, t);
  }
}

extern "C" void kernel_launch(void* const* d_in, const int* in_sizes, int n_in,
                              void* d_out, int out_size, void* d_ws, size_t ws_size,
                              hipStream_t stream) {
  const float* xyz1 = (const float*)d_in[0];
  const float* xyz2 = (const float*)d_in[1];
  float* out = (float*)d_out;

  char* ws = (char*)d_ws;
  unsigned short* Af = (unsigned short*)(ws);
  unsigned short* Bf = (unsigned short*)(ws + (size_t)2 * TOTAL * 32);
  unsigned*   minbuf = (unsigned*)(ws + (size_t)4 * TOTAL * 32);

  // 1) pack A/B forms for both sets + init minbuf + zero out
  pack_kernel<<<dim3(2 * TOTAL / TPB), dim3(TPB), 0, stream>>>(
      xyz1, xyz2, Af, Bf, minbuf, out);

  // 2) both directions, col-min only: 16 x 16 x 8 = 2048 blocks (8 waves/SIMD)
  dim3 mgrid(NPTS / COLS_PER_BLOCK, ROWCH, 2 * BATCH);
  min_kernel<<<mgrid, dim3(TPB), 0, stream>>>(Af, Bf, minbuf);

  // 3) finalize: mean(dist1) + mean(dist2)
  const float scale = 1.0f / (float)TOTAL;
  finalize_kernel<<<dim3(2 * TOTAL / TPB), dim3(TPB), 0, stream>>>(minbuf, out, scale);
}

// Round 8
// 38.100 us; speedup vs baseline: 3.3736x; 1.0329x over previous
//
#include <hip/hip_runtime.h>
#include <math.h>

#define BATCH 4
#define NPTS  8192
#define TOTAL (BATCH * NPTS)            // 32768 points per set
#define TPB   256

#define CT     4                        // fixed col-tiles per wave (32 cols each)
#define WPB    (TPB / 64)               // 4 waves per block
#define COLS_PER_WAVE  (32 * CT)        // 128
#define COLS_PER_BLOCK (COLS_PER_WAVE * WPB)  // 512
#define ROWCH  16                       // swept-row chunks (2048 blocks)
#define SWEEP  (NPTS / ROWCH)           // 512 rows swept per wave
#define NT     (SWEEP / 32)             // 16 A-tiles per sweep

typedef __bf16 bf16v8 __attribute__((ext_vector_type(8)));
typedef float  f32x16 __attribute__((ext_vector_type(16)));

// ws layout:
//   Af: ushort[2*TOTAL*16] @ 0    (2 MB)  A-form K-vectors, set1 then set2
//   Bf: ushort[2*TOTAL*16] @ 2 MB (2 MB)  B-form K-vectors, set1 then set2
//   minbuf: uint[2*TOTAL]  @ 4 MB (256 KB) dist1 then dist2
//   (min_kernel 2-deep prefetch may over-read Af by <=3KB into Bf -- mapped, harmless)

__device__ __forceinline__ unsigned f2ord(float f) {
  unsigned b = __float_as_uint(f);
  return ((int)b >= 0) ? (b ^ 0x80000000u) : ~b;
}
__device__ __forceinline__ float ord2f(unsigned k) {
  unsigned b = (k & 0x80000000u) ? (k ^ 0x80000000u) : ~k;
  return __uint_as_float(b);
}
__device__ __forceinline__ unsigned short f2bf(float f) {   // RNE
  unsigned u = __float_as_uint(f);
  return (unsigned short)((u + 0x7fffu + ((u >> 16) & 1u)) >> 16);
}
__device__ __forceinline__ float bf2f(unsigned short h) {
  return __uint_as_float(((unsigned)h) << 16);
}
// NO inline asm: minnum chains fuse to v_min3_f32 in ISel and can read
// MFMA dest registers in-place (no forced VGPR class / accvgpr moves).
__device__ __forceinline__ float mf3(float a, float b, float c) {
  return fminf(fminf(a, b), c);
}
// min over 16 acc elements folded with carry-in
__device__ __forceinline__ float coltree(const f32x16& a, float colt) {
  float t0 = mf3(a[0], a[1], a[2]);
  float t1 = mf3(a[3], a[4], a[5]);
  float t2 = mf3(a[6], a[7], a[8]);
  float t3 = mf3(a[9], a[10], a[11]);
  float t4 = mf3(a[12], a[13], a[14]);
  return mf3(colt, mf3(t0, t1, a[15]), mf3(t2, t3, t4));
}

// K-slot pairing (A[k]*B[k]), verified absmax 0 since R4:
//  k0-2: ah*ch   k3-5: al*ch   k6-8: ah*cl   (c = -2b)
//  k9,10: sq_a{h,l} * 1,1      k11,12: 1,1 * sq_b{h,l}     k13-15: 0
__global__ __launch_bounds__(TPB) void pack_kernel(
    const float* __restrict__ x1, const float* __restrict__ x2,
    unsigned short* __restrict__ Af, unsigned short* __restrict__ Bf,
    unsigned* __restrict__ minbuf, float* __restrict__ out) {
  int i = blockIdx.x * TPB + threadIdx.x;   // 0 .. 2*TOTAL-1  (set-major)
  if (i == 0) out[0] = 0.0f;
  minbuf[i] = 0xFFFFFFFFu;

  bool s2 = (i >= TOTAL);
  int j = s2 ? i - TOTAL : i;
  const float* src = s2 ? x2 : x1;
  float x = src[3 * j + 0];
  float y = src[3 * j + 1];
  float z = src[3 * j + 2];
  float sq = fmaf(x, x, fmaf(y, y, z * z));
  unsigned short sh = f2bf(sq);
  unsigned short sl = f2bf(sq - bf2f(sh));
  const unsigned short one = 0x3F80;

  unsigned short hx = f2bf(x), hy = f2bf(y), hz = f2bf(z);
  unsigned short lx = f2bf(x - bf2f(hx)), ly = f2bf(y - bf2f(hy)), lz = f2bf(z - bf2f(hz));
  float cx = -2.0f * x, cy = -2.0f * y, cz = -2.0f * z;
  unsigned short chx = f2bf(cx), chy = f2bf(cy), chz = f2bf(cz);
  unsigned short clx = f2bf(cx - bf2f(chx)), cly = f2bf(cy - bf2f(chy)), clz = f2bf(cz - bf2f(chz));

  // A-form
  {
    unsigned short v[16] = {hx, hy, hz, lx, ly, lz, hx, hy, hz,
                            sh, sl, one, one, 0, 0, 0};
    uint4* dst = (uint4*)(Af + (size_t)i * 16);
    uint4 w0, w1;
    w0.x = v[0] | ((unsigned)v[1] << 16);  w0.y = v[2] | ((unsigned)v[3] << 16);
    w0.z = v[4] | ((unsigned)v[5] << 16);  w0.w = v[6] | ((unsigned)v[7] << 16);
    w1.x = v[8] | ((unsigned)v[9] << 16);  w1.y = v[10] | ((unsigned)v[11] << 16);
    w1.z = v[12] | ((unsigned)v[13] << 16); w1.w = v[14] | ((unsigned)v[15] << 16);
    dst[0] = w0; dst[1] = w1;
  }
  // B-form
  {
    unsigned short v[16] = {chx, chy, chz, chx, chy, chz, clx, cly, clz,
                            one, one, sh, sl, 0, 0, 0};
    uint4* dst = (uint4*)(Bf + (size_t)i * 16);
    uint4 w0, w1;
    w0.x = v[0] | ((unsigned)v[1] << 16);  w0.y = v[2] | ((unsigned)v[3] << 16);
    w0.z = v[4] | ((unsigned)v[5] << 16);  w0.w = v[6] | ((unsigned)v[7] << 16);
    w1.x = v[8] | ((unsigned)v[9] << 16);  w1.y = v[10] | ((unsigned)v[11] << 16);
    w1.z = v[12] | ((unsigned)v[13] << 16); w1.w = v[14] | ((unsigned)v[15] << 16);
    dst[0] = w0; dst[1] = w1;
  }
}

// Col-min-only pass, both directions via blockIdx.z.
// dir=0: cols = set1 (B-form), sweep set2 (A-form) -> dist1
// dir=1: cols = set2,          sweep set1          -> dist2
__global__ __launch_bounds__(TPB) void min_kernel(
    const unsigned short* __restrict__ Af, const unsigned short* __restrict__ Bf,
    unsigned* __restrict__ minbuf) {
  const int z   = blockIdx.z;
  const int b   = z & (BATCH - 1);
  const int dir = z >> 2;
  const int tid = threadIdx.x;
  const int wave = tid >> 6, lane = tid & 63;
  const int g = lane >> 5, l31 = lane & 31;

  const int colset = dir * TOTAL;          // offset of the col (target) set
  const int rowset = TOTAL - colset;       // offset of the swept set
  const int colbase = blockIdx.x * COLS_PER_BLOCK + wave * COLS_PER_WAVE;
  const int rowbase = blockIdx.y * SWEEP;

  // fixed B fragments: CT col-tiles
  const bf16v8* bv = (const bf16v8*)Bf;
  bf16v8 bfr[CT];
#pragma unroll
  for (int t = 0; t < CT; ++t)
    bfr[t] = bv[(size_t)(colset + b * NPTS + colbase + t * 32 + l31) * 2 + g];

  f32x16 zc;
#pragma unroll
  for (int q = 0; q < 16; ++q) zc[q] = 0.0f;
  float colacc[CT];
#pragma unroll
  for (int t = 0; t < CT; ++t) colacc[t] = INFINITY;

  // swept A fragments; 2-deep software pipeline (unconditional over-read is
  // bounded by +3 tiles = 3KB past the region end, lands inside mapped ws)
  const bf16v8* ap = (const bf16v8*)Af + (size_t)(rowset + b * NPTS + rowbase + l31) * 2 + g;

  bf16v8 a0 = ap[0], a1 = ap[64];
  for (int ti = 0; ti < NT; ti += 2) {
    bf16v8 a2 = ap[128];
    bf16v8 a3 = ap[192];
#pragma unroll
    for (int t = 0; t < CT; ++t) {
      f32x16 acc = __builtin_amdgcn_mfma_f32_32x32x16_bf16(a0, bfr[t], zc, 0, 0, 0);
      colacc[t] = coltree(acc, colacc[t]);
    }
#pragma unroll
    for (int t = 0; t < CT; ++t) {
      f32x16 acc = __builtin_amdgcn_mfma_f32_32x32x16_bf16(a1, bfr[t], zc, 0, 0, 0);
      colacc[t] = coltree(acc, colacc[t]);
    }
    a0 = a2; a1 = a3;
    ap += 128;
  }

  // tail: merge g-halves (rows split across lane>>5), one masked atomic per tile
#pragma unroll
  for (int t = 0; t < CT; ++t) {
    float m = fminf(colacc[t], __shfl_xor(colacc[t], 32));
    if (g == 0)
      atomicMin(&minbuf[colset + b * NPTS + colbase + t * 32 + l31], f2ord(m));
  }
}

__global__ __launch_bounds__(TPB) void finalize_kernel(
    const unsigned* __restrict__ minbuf, float* __restrict__ out, float scale) {
  int idx = blockIdx.x * TPB + threadIdx.x;   // 0 .. 2*TOTAL-1
  float v = ord2f(minbuf[idx]) * scale;
  for (int off = 32; off > 0; off >>= 1) v += __shfl_down(v, off);
  __shared__ float ls[TPB / 64];
  if ((threadIdx.x & 63) == 0) ls[threadIdx.x >> 6] = v;
  __syncthreads();
  if (threadIdx.x == 0) {
    float t = 0.0f;
#pragma unroll
    for (int w = 0; w < TPB / 64; ++w) t += ls[w];
    atomicAdd(out, t);
  }
}

extern "C" void kernel_launch(void* const* d_in, const int* in_sizes, int n_in,
                              void* d_out, int out_size, void* d_ws, size_t ws_size,
                              hipStream_t stream) {
  const float* xyz1 = (const float*)d_in[0];
  const float* xyz2 = (const float*)d_in[1];
  float* out = (float*)d_out;

  char* ws = (char*)d_ws;
  unsigned short* Af = (unsigned short*)(ws);
  unsigned short* Bf = (unsigned short*)(ws + (size_t)2 * TOTAL * 32);
  unsigned*   minbuf = (unsigned*)(ws + (size_t)4 * TOTAL * 32);

  // 1) pack A/B forms for both sets + init minbuf + zero out
  pack_kernel<<<dim3(2 * TOTAL / TPB), dim3(TPB), 0, stream>>>(
      xyz1, xyz2, Af, Bf, minbuf, out);

  // 2) both directions, col-min only: 16 x 16 x 8 = 2048 blocks
  dim3 mgrid(NPTS / COLS_PER_BLOCK, ROWCH, 2 * BATCH);
  min_kernel<<<mgrid, dim3(TPB), 0, stream>>>(Af, Bf, minbuf);

  // 3) finalize: mean(dist1) + mean(dist2)
  const float scale = 1.0f / (float)TOTAL;
  finalize_kernel<<<dim3(2 * TOTAL / TPB), dim3(TPB), 0, stream>>>(minbuf, out, scale);
}

// Round 9
// 32.416 us; speedup vs baseline: 3.9651x; 1.1753x over previous
//
#include <hip/hip_runtime.h>
#include <math.h>

#define BATCH 4
#define NPTS  8192
#define TOTAL (BATCH * NPTS)            // 32768 points per set
#define TPB   256

#define CT     2                        // fixed col-tiles per wave (32 cols each)
#define WPB    (TPB / 64)               // 4 waves per block
#define COLS_PER_WAVE  (32 * CT)        // 64
#define COLS_PER_BLOCK (COLS_PER_WAVE * WPB)  // 256
#define ROWCH  16                       // swept-row chunks
#define SWEEP  (NPTS / ROWCH)           // 512 rows swept per wave
#define NT     (SWEEP / 32)             // 16 A-tiles per sweep

typedef __bf16 bf16v8 __attribute__((ext_vector_type(8)));
typedef float  f32x16 __attribute__((ext_vector_type(16)));

// ws layout:
//   Af: ushort[2*TOTAL*16] @ 0    (2 MB)  A-form K-vectors, set1 then set2
//   Bf: ushort[2*TOTAL*16] @ 2 MB (2 MB)  B-form K-vectors, set1 then set2
//   minbuf: uint[2*TOTAL]  @ 4 MB (256 KB) dist1 then dist2

__device__ __forceinline__ unsigned f2ord(float f) {
  unsigned b = __float_as_uint(f);
  return ((int)b >= 0) ? (b ^ 0x80000000u) : ~b;
}
__device__ __forceinline__ float ord2f(unsigned k) {
  unsigned b = (k & 0x80000000u) ? (k ^ 0x80000000u) : ~k;
  return __uint_as_float(b);
}
__device__ __forceinline__ unsigned short f2bf(float f) {   // RNE
  unsigned u = __float_as_uint(f);
  return (unsigned short)((u + 0x7fffu + ((u >> 16) & 1u)) >> 16);
}
__device__ __forceinline__ float bf2f(unsigned short h) {
  return __uint_as_float(((unsigned)h) << 16);
}
// min3-shaped fminf nesting (ISel fuses to v_min3_f32)
__device__ __forceinline__ float mf3(float a, float b, float c) {
  return fminf(fminf(a, b), c);
}
// min over 16 acc elements folded with carry-in
__device__ __forceinline__ float coltree(const f32x16& a, float colt) {
  float t0 = mf3(a[0], a[1], a[2]);
  float t1 = mf3(a[3], a[4], a[5]);
  float t2 = mf3(a[6], a[7], a[8]);
  float t3 = mf3(a[9], a[10], a[11]);
  float t4 = mf3(a[12], a[13], a[14]);
  return mf3(colt, mf3(t0, t1, a[15]), mf3(t2, t3, t4));
}

// K-slot pairing (A[k]*B[k]), verified absmax 0 since R4:
//  k0-2: ah*ch   k3-5: al*ch   k6-8: ah*cl   (c = -2b)
//  k9,10: sq_a{h,l} * 1,1      k11,12: 1,1 * sq_b{h,l}     k13-15: 0
__global__ __launch_bounds__(TPB) void pack_kernel(
    const float* __restrict__ x1, const float* __restrict__ x2,
    unsigned short* __restrict__ Af, unsigned short* __restrict__ Bf,
    unsigned* __restrict__ minbuf, float* __restrict__ out) {
  int i = blockIdx.x * TPB + threadIdx.x;   // 0 .. 2*TOTAL-1  (set-major)
  if (i == 0) out[0] = 0.0f;
  minbuf[i] = 0xFFFFFFFFu;

  bool s2 = (i >= TOTAL);
  int j = s2 ? i - TOTAL : i;
  const float* src = s2 ? x2 : x1;
  float x = src[3 * j + 0];
  float y = src[3 * j + 1];
  float z = src[3 * j + 2];
  float sq = fmaf(x, x, fmaf(y, y, z * z));
  unsigned short sh = f2bf(sq);
  unsigned short sl = f2bf(sq - bf2f(sh));
  const unsigned short one = 0x3F80;

  unsigned short hx = f2bf(x), hy = f2bf(y), hz = f2bf(z);
  unsigned short lx = f2bf(x - bf2f(hx)), ly = f2bf(y - bf2f(hy)), lz = f2bf(z - bf2f(hz));
  float cx = -2.0f * x, cy = -2.0f * y, cz = -2.0f * z;
  unsigned short chx = f2bf(cx), chy = f2bf(cy), chz = f2bf(cz);
  unsigned short clx = f2bf(cx - bf2f(chx)), cly = f2bf(cy - bf2f(chy)), clz = f2bf(cz - bf2f(chz));

  // A-form
  {
    unsigned short v[16] = {hx, hy, hz, lx, ly, lz, hx, hy, hz,
                            sh, sl, one, one, 0, 0, 0};
    uint4* dst = (uint4*)(Af + (size_t)i * 16);
    uint4 w0, w1;
    w0.x = v[0] | ((unsigned)v[1] << 16);  w0.y = v[2] | ((unsigned)v[3] << 16);
    w0.z = v[4] | ((unsigned)v[5] << 16);  w0.w = v[6] | ((unsigned)v[7] << 16);
    w1.x = v[8] | ((unsigned)v[9] << 16);  w1.y = v[10] | ((unsigned)v[11] << 16);
    w1.z = v[12] | ((unsigned)v[13] << 16); w1.w = v[14] | ((unsigned)v[15] << 16);
    dst[0] = w0; dst[1] = w1;
  }
  // B-form
  {
    unsigned short v[16] = {chx, chy, chz, chx, chy, chz, clx, cly, clz,
                            one, one, sh, sl, 0, 0, 0};
    uint4* dst = (uint4*)(Bf + (size_t)i * 16);
    uint4 w0, w1;
    w0.x = v[0] | ((unsigned)v[1] << 16);  w0.y = v[2] | ((unsigned)v[3] << 16);
    w0.z = v[4] | ((unsigned)v[5] << 16);  w0.w = v[6] | ((unsigned)v[7] << 16);
    w1.x = v[8] | ((unsigned)v[9] << 16);  w1.y = v[10] | ((unsigned)v[11] << 16);
    w1.z = v[12] | ((unsigned)v[13] << 16); w1.w = v[14] | ((unsigned)v[15] << 16);
    dst[0] = w0; dst[1] = w1;
  }
}

// Col-min-only pass, both directions via blockIdx.z.
// dir=0: cols = set1 (B-form), sweep set2 (A-form) -> dist1
// dir=1: cols = set2,          sweep set1          -> dist2
// __launch_bounds__(256, 6): cap regs (~85) so acc stays VGPR-class and
// ~6 waves/SIMD are resident to hide MFMA->VALU latency.
__global__ __launch_bounds__(TPB, 6) void min_kernel(
    const unsigned short* __restrict__ Af, const unsigned short* __restrict__ Bf,
    unsigned* __restrict__ minbuf) {
  const int z   = blockIdx.z;
  const int b   = z & (BATCH - 1);
  const int dir = z >> 2;
  const int tid = threadIdx.x;
  const int wave = tid >> 6, lane = tid & 63;
  const int g = lane >> 5, l31 = lane & 31;

  const int colset = dir * TOTAL;          // offset of the col (target) set
  const int rowset = TOTAL - colset;       // offset of the swept set
  const int colbase = blockIdx.x * COLS_PER_BLOCK + wave * COLS_PER_WAVE;
  const int rowbase = blockIdx.y * SWEEP;

  // fixed B fragments: CT col-tiles
  const bf16v8* bv = (const bf16v8*)Bf;
  bf16v8 bfr0 = bv[(size_t)(colset + b * NPTS + colbase + l31) * 2 + g];
  bf16v8 bfr1 = bv[(size_t)(colset + b * NPTS + colbase + 32 + l31) * 2 + g];

  f32x16 zc;
#pragma unroll
  for (int q = 0; q < 16; ++q) zc[q] = 0.0f;
  float colacc0 = INFINITY, colacc1 = INFINITY;

  const bf16v8* ap = (const bf16v8*)Af + (size_t)(rowset + b * NPTS + rowbase + l31) * 2 + g;

  for (int ti = 0; ti < NT; ++ti) {
    bf16v8 a = ap[0];
    f32x16 acc0 = __builtin_amdgcn_mfma_f32_32x32x16_bf16(a, bfr0, zc, 0, 0, 0);
    f32x16 acc1 = __builtin_amdgcn_mfma_f32_32x32x16_bf16(a, bfr1, zc, 0, 0, 0);
    colacc0 = coltree(acc0, colacc0);
    colacc1 = coltree(acc1, colacc1);
    ap += 64;
  }

  // tail: merge g-halves (rows split across lane>>5), one masked atomic per tile
  {
    float m0 = fminf(colacc0, __shfl_xor(colacc0, 32));
    float m1 = fminf(colacc1, __shfl_xor(colacc1, 32));
    if (g == 0) {
      atomicMin(&minbuf[colset + b * NPTS + colbase + l31], f2ord(m0));
      atomicMin(&minbuf[colset + b * NPTS + colbase + 32 + l31], f2ord(m1));
    }
  }
}

__global__ __launch_bounds__(TPB) void finalize_kernel(
    const unsigned* __restrict__ minbuf, float* __restrict__ out, float scale) {
  int idx = blockIdx.x * TPB + threadIdx.x;   // 0 .. 2*TOTAL-1
  float v = ord2f(minbuf[idx]) * scale;
  for (int off = 32; off > 0; off >>= 1) v += __shfl_down(v, off);
  __shared__ float ls[TPB / 64];
  if ((threadIdx.x & 63) == 0) ls[threadIdx.x >> 6] = v;
  __syncthreads();
  if (threadIdx.x == 0) {
    float t = 0.0f;
#pragma unroll
    for (int w = 0; w < TPB / 64; ++w) t += ls[w];
    atomicAdd(out, t);
  }
}

extern "C" void kernel_launch(void* const* d_in, const int* in_sizes, int n_in,
                              void* d_out, int out_size, void* d_ws, size_t ws_size,
                              hipStream_t stream) {
  const float* xyz1 = (const float*)d_in[0];
  const float* xyz2 = (const float*)d_in[1];
  float* out = (float*)d_out;

  char* ws = (char*)d_ws;
  unsigned short* Af = (unsigned short*)(ws);
  unsigned short* Bf = (unsigned short*)(ws + (size_t)2 * TOTAL * 32);
  unsigned*   minbuf = (unsigned*)(ws + (size_t)4 * TOTAL * 32);

  // 1) pack A/B forms for both sets + init minbuf + zero out
  pack_kernel<<<dim3(2 * TOTAL / TPB), dim3(TPB), 0, stream>>>(
      xyz1, xyz2, Af, Bf, minbuf, out);

  // 2) both directions, col-min only: 32 x 16 x 8 = 4096 blocks
  dim3 mgrid(NPTS / COLS_PER_BLOCK, ROWCH, 2 * BATCH);
  min_kernel<<<mgrid, dim3(TPB), 0, stream>>>(Af, Bf, minbuf);

  // 3) finalize: mean(dist1) + mean(dist2)
  const float scale = 1.0f / (float)TOTAL;
  finalize_kernel<<<dim3(2 * TOTAL / TPB), dim3(TPB), 0, stream>>>(minbuf, out, scale);
}